// Round 3
// baseline (858.424 us; speedup 1.0000x reference)
//
#include <hip/hip_runtime.h>
#include <hip/hip_bf16.h>

typedef float  f32x4 __attribute__((ext_vector_type(4)));
typedef short  s16x8 __attribute__((ext_vector_type(8)));

#define NEGBIG -1e30f

__device__ __forceinline__ unsigned short f2b(float f) {
    union { float f; unsigned u; } c; c.f = f;
    unsigned r = c.u + 0x7FFF + ((c.u >> 16) & 1);
    return (unsigned short)(r >> 16);
}
__device__ __forceinline__ float b2f(unsigned short h) {
    union { unsigned u; float f; } c; c.u = ((unsigned)h) << 16;
    return c.f;
}
__device__ __forceinline__ float sigm(float x) { return 1.f / (1.f + __expf(-x)); }

// coherent (agent-scope) accessors: bypass per-XCD L1/L2, hit memory-side L3.
__device__ __forceinline__ s16x8 ld_b128_sc(const unsigned short* p) {
    s16x8 r;
    asm volatile("global_load_dwordx4 %0, %1, off sc0 sc1" : "=v"(r) : "v"(p));
    return r;
}
__device__ __forceinline__ void st_short_sc(unsigned short* p, unsigned short v) {
    unsigned int dv = v;
    asm volatile("global_store_short %0, %1, off sc0 sc1" :: "v"(p), "v"(dv) : "memory");
}

// Poll a wave's 16 af chunks from BASE until no element equals the 0xFFFF poison.
// The loads ARE the data loads: one L3 round trip in the common case.
// sched_barrier after the waitcnt per rule #18 (asm loads aren't dep-tracked vs MFMA).
#define POLL_H(BASE, AF) do {                                                        \
    unsigned okm_ = 0; int guard_ = 0;                                               \
    while (true) {                                                                   \
        _Pragma("unroll")                                                            \
        for (int kk_ = 0; kk_ < 16; ++kk_)                                           \
            if (!((okm_ >> kk_) & 1)) AF[kk_] = ld_b128_sc((BASE) + kk_ * 32);       \
        asm volatile("s_waitcnt vmcnt(0)" ::: "memory");                             \
        __builtin_amdgcn_sched_barrier(0);                                           \
        _Pragma("unroll")                                                            \
        for (int kk_ = 0; kk_ < 16; ++kk_) if (!((okm_ >> kk_) & 1)) {               \
            bool bad_ = false;                                                       \
            _Pragma("unroll")                                                        \
            for (int e_ = 0; e_ < 8; ++e_)                                           \
                bad_ = bad_ || ((unsigned short)AF[kk_][e_] == (unsigned short)0xFFFFu); \
            if (!bad_) okm_ |= (1u << kk_);                                          \
        }                                                                            \
        if (__all(okm_ == 0xFFFFu)) break;                                           \
        if (++guard_ > (1 << 18)) break;  /* safety: no hang */                      \
    }                                                                                \
    __builtin_amdgcn_sched_barrier(0);                                               \
} while (0)

// ---------------------------------------------------------------- init
__global__ void init_zero(int* flags, unsigned short* hb0, unsigned short* hb1, unsigned short* hb2) {
    int idx = blockIdx.x * 256 + threadIdx.x;
    int stride = gridDim.x * 256;
    for (int i = idx; i < 1024; i += stride) flags[i] = 0;
    for (int i = idx; i < 32768; i += stride) {
        hb0[i] = 0;               // h_{-1} = 0 (valid data: passes poison check immediately)
        hb1[i] = 0xFFFFu;         // poison
        hb2[i] = 0xFFFFu;         // poison
    }
}

// ---------------------------------------------------------------- prep weights (bf16 casts + Wqkv concat-transpose)
__global__ void prep_w(const float* Wq, const float* Wk, const float* Wv,
                       const float* gWih, const float* gWhh,
                       unsigned short* wcat, unsigned short* wih, unsigned short* whh) {
    int idx = blockIdx.x * 256 + threadIdx.x;
    int stride = gridDim.x * 256;
    const int N1 = 131072, N2 = 491520, N3 = 786432;
    for (; idx < N1 + N2 + N3; idx += stride) {
        if (idx < N1) {
            int n = idx >> 8, k = idx & 255;
            float v;
            if (n < 128) v = Wq[k * 128 + n];
            else if (n < 256) v = Wk[k * 128 + (n - 128)];
            else v = Wv[k * 256 + (n - 256)];
            wcat[n * 256 + k] = f2b(v);
        } else if (idx < N1 + N2) {
            int i = idx - N1; wih[i] = f2b(gWih[i]);
        } else {
            int i = idx - N1 - N2; whh[i] = f2b(gWhh[i]);
        }
    }
}

// ---------------------------------------------------------------- prep E^T  [256][4096] bf16
__global__ __launch_bounds__(256) void prep_et(const float* code_emb, const int* ct0, const int* ct1, const int* ct2,
                                               const float* t0e, const float* t1e, const float* t2e,
                                               unsigned short* ET) {
    __shared__ float tile[64][65];
    const int d0 = blockIdx.x * 64, c0 = blockIdx.y * 64;
    const int t = threadIdx.x;
    for (int p = 0; p < 16; ++p) {
        int idx = p * 256 + t;
        int dl = idx & 63, cl = idx >> 6;   // cl in [0,64) over passes
        int code = c0 + cl + 1;
        int d = d0 + dl;
        float v = code_emb[code * 256 + d] + t0e[ct0[code] * 256 + d]
                + t1e[ct1[code] * 256 + d] + t2e[ct2[code] * 256 + d];
        tile[dl][cl] = v;
    }
    __syncthreads();
    for (int p = 0; p < 2; ++p) {
        int idx = p * 256 + t;
        int dl = idx >> 3, ch = idx & 7;
        s16x8 pk;
#pragma unroll
        for (int e = 0; e < 8; ++e) pk[e] = (short)f2b(tile[dl][ch * 8 + e]);
        *(s16x8*)(ET + (size_t)(d0 + dl) * 4096 + c0 + ch * 8) = pk;
    }
}

// ---------------------------------------------------------------- encoder GEMM: v = mask*( (code_x>0) @ E ) / counts
__global__ __launch_bounds__(256) void enc_gemm(const float* code_x, const unsigned short* ET,
                                                const int* lens, unsigned short* Vb) {
    __shared__ __align__(16) char sm[4096 + 32768 + 128];
    char* As = sm;
    char* Bs = sm + 4096;
    float* cl = (float*)(sm + 4096 + 32768);
    const int m0 = blockIdx.x * 32;
    const int t = threadIdx.x, l = t & 63, w = t >> 6;
    const int lr = l & 15, lq = l >> 4, l7 = l & 7;
    const int sr = t >> 3, sc = t & 7;
    f32x4 acc[2][4];
#pragma unroll
    for (int a = 0; a < 2; ++a)
#pragma unroll
        for (int b = 0; b < 4; ++b) acc[a][b] = (f32x4){0.f, 0.f, 0.f, 0.f};
    int cnt = 0;
    for (int it = 0; it < 64; ++it) {
        const int k0 = it * 64;
        const float* ga = code_x + (size_t)(m0 + sr) * 4096 + k0 + sc * 8;
        f32x4 a0 = *(const f32x4*)ga;
        f32x4 a1 = *(const f32x4*)(ga + 4);
        s16x8 ap;
#pragma unroll
        for (int e = 0; e < 4; ++e) { bool on = a0[e] > 0.f; ap[e] = on ? (short)0x3F80 : (short)0; cnt += on ? 1 : 0; }
#pragma unroll
        for (int e = 0; e < 4; ++e) { bool on = a1[e] > 0.f; ap[4 + e] = on ? (short)0x3F80 : (short)0; cnt += on ? 1 : 0; }
        *(s16x8*)(As + sr * 128 + ((sc ^ (sr & 7)) << 4)) = ap;
#pragma unroll
        for (int rd = 0; rd < 8; ++rd) {
            int i = rd * 256 + t;
            int n = i >> 3, cc = i & 7;
            s16x8 bv = *(const s16x8*)(ET + (size_t)n * 4096 + k0 + cc * 8);
            *(s16x8*)(Bs + n * 128 + ((cc ^ (n & 7)) << 4)) = bv;
        }
        __syncthreads();
#pragma unroll
        for (int kk = 0; kk < 2; ++kk) {
            const int cp = kk * 4 + lq;
            s16x8 af[2], bf[4];
#pragma unroll
            for (int mt = 0; mt < 2; ++mt)
                af[mt] = *(const s16x8*)(As + (mt * 16 + lr) * 128 + ((cp ^ l7) << 4));
#pragma unroll
            for (int nt = 0; nt < 4; ++nt)
                bf[nt] = *(const s16x8*)(Bs + ((w * 4 + nt) * 16 + lr) * 128 + ((cp ^ l7) << 4));
#pragma unroll
            for (int mt = 0; mt < 2; ++mt)
#pragma unroll
                for (int nt = 0; nt < 4; ++nt)
                    acc[mt][nt] = __builtin_amdgcn_mfma_f32_16x16x32_bf16(af[mt], bf[nt], acc[mt][nt], 0, 0, 0);
        }
        __syncthreads();
    }
    float fc = (float)cnt;
    fc += __shfl_xor(fc, 1); fc += __shfl_xor(fc, 2); fc += __shfl_xor(fc, 4);
    if (sc == 0) cl[sr] = fmaxf(fc, 1.f);
    __syncthreads();
#pragma unroll
    for (int mt = 0; mt < 2; ++mt)
#pragma unroll
        for (int i = 0; i < 4; ++i) {
            int m = mt * 16 + lq * 4 + i;
            int gm = m0 + m;
            float rc = 1.f / cl[m];
            unsigned bi = (unsigned)gm / 100u;
            unsigned vi = (unsigned)gm - bi * 100u;
            float msk = ((int)vi < lens[bi]) ? 1.f : 0.f;
#pragma unroll
            for (int nt = 0; nt < 4; ++nt) {
                int n = (w * 4 + nt) * 16 + lr;
                Vb[(size_t)gm * 256 + n] = f2b(acc[mt][nt][i] * rc * msk);
            }
        }
}

// ---------------------------------------------------------------- generic bf16 GEMM (A[M][K] @ B[N][K]^T), M tiled by 32, N by 256
// mode 1: out bf16 plain + bias; mode 2: out bf16 plain, no bias
__global__ __launch_bounds__(256) void gemm_bf16(const unsigned short* A, const unsigned short* Bm,
                                                 int K, int Ntot, int mode,
                                                 unsigned short* outp, const float* bias) {
    __shared__ __align__(16) char sm[4096 + 32768];
    char* As = sm;
    char* Bs = sm + 4096;
    const int m0 = blockIdx.x * 32;
    const int n0 = blockIdx.y * 256;
    const int t = threadIdx.x, l = t & 63, w = t >> 6;
    const int lr = l & 15, lq = l >> 4, l7 = l & 7;
    const int sr = t >> 3, sc = t & 7;
    const int iters = K >> 6;
    f32x4 acc[2][4];
#pragma unroll
    for (int a = 0; a < 2; ++a)
#pragma unroll
        for (int b = 0; b < 4; ++b) acc[a][b] = (f32x4){0.f, 0.f, 0.f, 0.f};
    for (int it = 0; it < iters; ++it) {
        const int k0 = it * 64;
        s16x8 av = *(const s16x8*)(A + (size_t)(m0 + sr) * K + k0 + sc * 8);
        *(s16x8*)(As + sr * 128 + ((sc ^ (sr & 7)) << 4)) = av;
#pragma unroll
        for (int rd = 0; rd < 8; ++rd) {
            int i = rd * 256 + t;
            int n = i >> 3, cc = i & 7;
            s16x8 bv = *(const s16x8*)(Bm + (size_t)(n0 + n) * K + k0 + cc * 8);
            *(s16x8*)(Bs + n * 128 + ((cc ^ (n & 7)) << 4)) = bv;
        }
        __syncthreads();
#pragma unroll
        for (int kk = 0; kk < 2; ++kk) {
            const int cp = kk * 4 + lq;
            s16x8 af[2], bf[4];
#pragma unroll
            for (int mt = 0; mt < 2; ++mt)
                af[mt] = *(const s16x8*)(As + (mt * 16 + lr) * 128 + ((cp ^ l7) << 4));
#pragma unroll
            for (int nt = 0; nt < 4; ++nt)
                bf[nt] = *(const s16x8*)(Bs + ((w * 4 + nt) * 16 + lr) * 128 + ((cp ^ l7) << 4));
#pragma unroll
            for (int mt = 0; mt < 2; ++mt)
#pragma unroll
                for (int nt = 0; nt < 4; ++nt)
                    acc[mt][nt] = __builtin_amdgcn_mfma_f32_16x16x32_bf16(af[mt], bf[nt], acc[mt][nt], 0, 0, 0);
        }
        __syncthreads();
    }
#pragma unroll
    for (int mt = 0; mt < 2; ++mt)
#pragma unroll
        for (int i = 0; i < 4; ++i) {
            int gm = m0 + mt * 16 + lq * 4 + i;
#pragma unroll
            for (int nt = 0; nt < 4; ++nt) {
                int n = n0 + (w * 4 + nt) * 16 + lr;
                float v = acc[mt][nt][i];
                if (mode == 1) v += bias[n];
                outp[(size_t)gm * Ntot + n] = f2b(v);
            }
        }
}

// ---------------------------------------------------------------- attention (one block per batch) + time-emb concat
__global__ __launch_bounds__(256) void attn_kernel(const unsigned short* QKV, const int* lens,
                                                   const float* intervals, const float* time_w, const float* time_b,
                                                   unsigned short* X) {
    __shared__ __align__(16) char sm[28672 + 32768];
    char* Pb = sm;            // P: 112 rows x 128 cols bf16, pitch 256B, swizzled
    char* VTb = sm + 28672;   // V^T half: 128 d x 128 j bf16, pitch 256B, swizzled
    const int b = blockIdx.x;
    const int t = threadIdx.x, l = t & 63, w = t >> 6;
    const int lr = l & 15, lq = l >> 4;
    const int lenb = lens[b];
    // zero P
    for (int p = 0; p < 7; ++p) {
        int idx = p * 256 + t;
        *(f32x4*)(Pb + idx * 16) = (f32x4){0.f, 0.f, 0.f, 0.f};
    }
    __syncthreads();
    // ---- S = Q K^T  (rows 2w..2w+1 tiles of 16; wave 3 handles tile 6 only)
    f32x4 S[2][7];
#pragma unroll
    for (int a = 0; a < 2; ++a)
#pragma unroll
        for (int c = 0; c < 7; ++c) S[a][c] = (f32x4){0.f, 0.f, 0.f, 0.f};
#pragma unroll
    for (int kk = 0; kk < 4; ++kk) {
        s16x8 qa[2], kb[7];
#pragma unroll
        for (int mi = 0; mi < 2; ++mi) {
            int mt = 2 * w + mi;
            if (mt > 6) continue;
            int row = b * 100 + mt * 16 + lr;
            qa[mi] = *(const s16x8*)(QKV + (size_t)row * 512 + kk * 32 + lq * 8);
        }
#pragma unroll
        for (int nt = 0; nt < 7; ++nt) {
            int row = b * 100 + nt * 16 + lr;
            kb[nt] = *(const s16x8*)(QKV + (size_t)row * 512 + 128 + kk * 32 + lq * 8);
        }
#pragma unroll
        for (int mi = 0; mi < 2; ++mi) {
            int mt = 2 * w + mi;
            if (mt > 6) continue;
#pragma unroll
            for (int nt = 0; nt < 7; ++nt)
                S[mi][nt] = __builtin_amdgcn_mfma_f32_16x16x32_bf16(qa[mi], kb[nt], S[mi][nt], 0, 0, 0);
        }
    }
    // ---- softmax rows (all in shuffle groups of 16), store P to LDS
#pragma unroll
    for (int mi = 0; mi < 2; ++mi) {
        int mt = 2 * w + mi;
        if (mt > 6) continue;
        float sv[7][4];
#pragma unroll
        for (int nt = 0; nt < 7; ++nt) {
            int j = nt * 16 + lr;
#pragma unroll
            for (int i = 0; i < 4; ++i)
                sv[nt][i] = (j < lenb) ? S[mi][nt][i] : NEGBIG;
        }
#pragma unroll
        for (int i = 0; i < 4; ++i) {
            float mx = sv[0][i];
#pragma unroll
            for (int nt = 1; nt < 7; ++nt) mx = fmaxf(mx, sv[nt][i]);
            mx = fmaxf(mx, __shfl_xor(mx, 1));
            mx = fmaxf(mx, __shfl_xor(mx, 2));
            mx = fmaxf(mx, __shfl_xor(mx, 4));
            mx = fmaxf(mx, __shfl_xor(mx, 8));
            float e[7], sum = 0.f;
#pragma unroll
            for (int nt = 0; nt < 7; ++nt) { e[nt] = __expf(sv[nt][i] - mx); sum += e[nt]; }
            sum += __shfl_xor(sum, 1);
            sum += __shfl_xor(sum, 2);
            sum += __shfl_xor(sum, 4);
            sum += __shfl_xor(sum, 8);
            float rs = 1.f / sum;
            int m = mt * 16 + lq * 4 + i;
#pragma unroll
            for (int nt = 0; nt < 7; ++nt) {
                int j = nt * 16 + lr;
                *(unsigned short*)(Pb + m * 256 + (((j >> 3) ^ (m & 7)) << 4) + ((j & 7) << 1)) = f2b(e[nt] * rs);
            }
        }
    }
    __syncthreads();
    // ---- O = P @ V + V, two halves of d
    for (int h = 0; h < 2; ++h) {
        for (int p = 0; p < 8; ++p) {
            int idx = p * 256 + t;
            *(f32x4*)(VTb + idx * 16) = (f32x4){0.f, 0.f, 0.f, 0.f};
        }
        __syncthreads();
        for (int p = 0; p < 7; ++p) {
            int ci = p * 256 + t;
            if (ci < 1600) {
                int j = ci >> 4, d8 = ci & 15;
                s16x8 vv = *(const s16x8*)(QKV + (size_t)(b * 100 + j) * 512 + 256 + h * 128 + d8 * 8);
#pragma unroll
                for (int e = 0; e < 8; ++e) {
                    int dl = d8 * 8 + e;
                    *(unsigned short*)(VTb + dl * 256 + (((j >> 3) ^ (dl & 7)) << 4) + ((j & 7) << 1)) = (unsigned short)vv[e];
                }
            }
        }
        __syncthreads();
        f32x4 O[2][8];
#pragma unroll
        for (int a = 0; a < 2; ++a)
#pragma unroll
            for (int c = 0; c < 8; ++c) O[a][c] = (f32x4){0.f, 0.f, 0.f, 0.f};
#pragma unroll
        for (int kk = 0; kk < 4; ++kk) {
            s16x8 pa[2];
#pragma unroll
            for (int mi = 0; mi < 2; ++mi) {
                int mt = 2 * w + mi;
                if (mt > 6) continue;
                int m = mt * 16 + lr;
                pa[mi] = *(const s16x8*)(Pb + m * 256 + (((kk * 4 + lq) ^ (m & 7)) << 4));
            }
#pragma unroll
            for (int nt = 0; nt < 8; ++nt) {
                int dl = nt * 16 + lr;
                s16x8 vb = *(const s16x8*)(VTb + dl * 256 + (((kk * 4 + lq) ^ (dl & 7)) << 4));
#pragma unroll
                for (int mi = 0; mi < 2; ++mi) {
                    int mt = 2 * w + mi;
                    if (mt > 6) continue;
                    O[mi][nt] = __builtin_amdgcn_mfma_f32_16x16x32_bf16(pa[mi], vb, O[mi][nt], 0, 0, 0);
                }
            }
        }
#pragma unroll
        for (int mi = 0; mi < 2; ++mi) {
            int mt = 2 * w + mi;
            if (mt > 6) continue;
#pragma unroll
            for (int i = 0; i < 4; ++i) {
                int m = mt * 16 + lq * 4 + i;
                if (m < 100) {
#pragma unroll
                    for (int nt = 0; nt < 8; ++nt) {
                        int dl = nt * 16 + lr;
                        float res = b2f(*(unsigned short*)(VTb + dl * 256 + (((m >> 3) ^ (dl & 7)) << 4) + ((m & 7) << 1)));
                        X[(size_t)(b * 100 + m) * 320 + h * 128 + dl] = f2b(O[mi][nt][i] + res);
                    }
                }
            }
        }
        if (h == 0) __syncthreads();
    }
    // ---- time embedding
    for (int p = 0; p < 25; ++p) {
        int idx = p * 256 + t;
        int m = idx >> 6, d = idx & 63;
        float val = intervals[b * 100 + m] * time_w[d] + time_b[d];
        X[(size_t)(b * 100 + m) * 320 + 256 + d] = f2b(val);
    }
}

// ---------------------------------------------------------------- GRU recurrence + classifier.
// Sync protocol: NO flags, NO fences. 3 rotating h buffers; "not yet written" is encoded
// in the data itself as bf16 0xFFFF poison (NaN pattern; f2b(finite) never produces it;
// stores are 2B atomic units so per-short checks are tear-free). Per step:
//   poll rb (the poll loads ARE the af loads: 1 L3 round trip)  ->
//   poison pb (safe: h_{s-1} observed => everyone finished reading h_{s-2}) ->
//   MFMA -> elementwise -> store h_s to wb (no drain: readers wait on the data;
//   our next poll's vmcnt(0) drains poison before the next publish, preserving the
//   poison-before-data visibility invariant).
__global__ __launch_bounds__(256, 1) void gru_kernel(const unsigned short* GIb, const unsigned short* WHH,
                                                     const float* gbhh, const int* lens,
                                                     unsigned short* hbA, unsigned short* hbB, unsigned short* hbC,
                                                     const float* clsW, const float* clsb, float* out) {
    const int bid = blockIdx.x;
    const int t = threadIdx.x, l = t & 63, w = t >> 6;
    const int lr = l & 15, lq = l >> 4;
    const int j = bid * 16 + lr;
    // max length (uniform across blocks)
    int ml;
    {
        int v = lens[l];
        v = max(v, __shfl_xor(v, 1));  v = max(v, __shfl_xor(v, 2));
        v = max(v, __shfl_xor(v, 4));  v = max(v, __shfl_xor(v, 8));
        v = max(v, __shfl_xor(v, 16)); v = max(v, __shfl_xor(v, 32));
        ml = v;
    }
    int lens4[4];
#pragma unroll
    for (int i = 0; i < 4; ++i) lens4[i] = lens[w * 16 + lq * 4 + i];
    const float bhr = gbhh[j], bhz = gbhh[512 + j], bhn = gbhh[1024 + j];
    // Whh fragment slice: 3 gates x 16 k-steps (read-only, plain cached loads)
    s16x8 Bf[3][16];
#pragma unroll
    for (int g = 0; g < 3; ++g)
#pragma unroll
        for (int kk = 0; kk < 16; ++kk)
            Bf[g][kk] = *(const s16x8*)(WHH + (size_t)(g * 512 + j) * 512 + kk * 32 + lq * 8);
    float ho[4] = {0.f, 0.f, 0.f, 0.f};
    size_t gi_base[4];
    size_t hrow[4];
#pragma unroll
    for (int i = 0; i < 4; ++i) {
        gi_base[i] = (size_t)((w * 16 + lq * 4 + i) * 100) * 1536 + j;
        hrow[i]    = (size_t)(w * 16 + lq * 4 + i) * 512 + j;
    }
    const size_t arow = (size_t)(w * 16 + lr) * 512 + lq * 8;

    // prefetch gi for step 0 (plain cached loads; GIb read-only)
    float gir[4], giz[4], gin[4];
#pragma unroll
    for (int i = 0; i < 4; ++i) {
        const unsigned short* gp = GIb + gi_base[i];
        gir[i] = b2f(gp[0]); giz[i] = b2f(gp[512]); gin[i] = b2f(gp[1024]);
    }

    // rotating buffers: rb holds h_{s-1}, wb receives h_s, pb gets poisoned for h_{s+2}.
    unsigned short* rb = hbA;   // zeros initially (h_{-1})
    unsigned short* wb = hbB;   // pre-poisoned by init_zero
    unsigned short* pb = hbC;   // pre-poisoned by init_zero

    for (int step = 0; step < ml; ++step) {
        s16x8 af[16];
        POLL_H(rb + arow, af);
        // poison pb (this thread's own 4 h-slots); drained by next step's poll vmcnt(0)
#pragma unroll
        for (int i = 0; i < 4; ++i) st_short_sc(pb + hrow[i], (unsigned short)0xFFFFu);
        f32x4 ar = (f32x4){0.f,0.f,0.f,0.f}, az = ar, an = ar;
#pragma unroll
        for (int kk = 0; kk < 16; ++kk) {
            ar = __builtin_amdgcn_mfma_f32_16x16x32_bf16(af[kk], Bf[0][kk], ar, 0, 0, 0);
            az = __builtin_amdgcn_mfma_f32_16x16x32_bf16(af[kk], Bf[1][kk], az, 0, 0, 0);
            an = __builtin_amdgcn_mfma_f32_16x16x32_bf16(af[kk], Bf[2][kk], an, 0, 0, 0);
        }
#pragma unroll
        for (int i = 0; i < 4; ++i) {
            float r = sigm(gir[i] + ar[i] + bhr);
            float z = sigm(giz[i] + az[i] + bhz);
            float n = tanhf(gin[i] + r * (an[i] + bhn));
            float hv = (step < lens4[i]) ? ((1.f - z) * n + z * ho[i]) : ho[i];
            ho[i] = hv;
            st_short_sc(wb + hrow[i], f2b(hv));   // no drain: readers poll the data
        }
        // prefetch next gi (overlaps into next poll)
        if (step + 1 < ml) {
#pragma unroll
            for (int i = 0; i < 4; ++i) {
                const unsigned short* gp = GIb + gi_base[i] + (size_t)(step + 1) * 1536;
                gir[i] = b2f(gp[0]); giz[i] = b2f(gp[512]); gin[i] = b2f(gp[1024]);
            }
        }
        unsigned short* tmp = rb; rb = wb; wb = pb; pb = tmp;
    }

    // classifier: 30 blocks, each 3 output columns, over the final h (bf16, buf[ml%3] == rb).
    // The data-poll doubles as the final grid barrier: this wave's poll covers exactly the
    // batch rows (t>>2 in [16w,16w+16)) its classifier threads read.
    if (bid < 30) {
        {
            s16x8 af[16];
            POLL_H(rb + arow, af);
        }
        const unsigned short* fbuf = rb;   // plain cached loads are safe: no stale L1/L2
                                           // lines exist (fbuf only touched via sc this dispatch)
        int bb = t >> 2, qq = t & 3;
        int c0 = bid * 3;
        float s0 = 0.f, s1 = 0.f, s2 = 0.f;
        for (int kc = 0; kc < 16; ++kc) {
            int k = qq * 128 + kc * 8;
            s16x8 hvb = *(const s16x8*)(fbuf + (size_t)bb * 512 + k);
            f32x4 w0a = *(const f32x4*)(clsW + (size_t)(c0 + 0) * 512 + k);
            f32x4 w0b = *(const f32x4*)(clsW + (size_t)(c0 + 0) * 512 + k + 4);
            f32x4 w1a = *(const f32x4*)(clsW + (size_t)(c0 + 1) * 512 + k);
            f32x4 w1b = *(const f32x4*)(clsW + (size_t)(c0 + 1) * 512 + k + 4);
            f32x4 w2a = *(const f32x4*)(clsW + (size_t)(c0 + 2) * 512 + k);
            f32x4 w2b = *(const f32x4*)(clsW + (size_t)(c0 + 2) * 512 + k + 4);
#pragma unroll
            for (int e = 0; e < 4; ++e) {
                float h0 = b2f((unsigned short)hvb[e]);
                float h1 = b2f((unsigned short)hvb[4 + e]);
                s0 += h0 * w0a[e] + h1 * w0b[e];
                s1 += h0 * w1a[e] + h1 * w1b[e];
                s2 += h0 * w2a[e] + h1 * w2b[e];
            }
        }
        s0 += __shfl_xor(s0, 1); s0 += __shfl_xor(s0, 2);
        s1 += __shfl_xor(s1, 1); s1 += __shfl_xor(s1, 2);
        s2 += __shfl_xor(s2, 1); s2 += __shfl_xor(s2, 2);
        if (qq == 0) {
            out[bb * 90 + c0 + 0] = sigm(s0 + clsb[c0 + 0]);
            out[bb * 90 + c0 + 1] = sigm(s1 + clsb[c0 + 1]);
            out[bb * 90 + c0 + 2] = sigm(s2 + clsb[c0 + 2]);
        }
    }
}

// ---------------------------------------------------------------- launch
extern "C" void kernel_launch(void* const* d_in, const int* in_sizes, int n_in,
                              void* d_out, int out_size, void* d_ws, size_t ws_size,
                              hipStream_t stream) {
    const float* code_x   = (const float*)d_in[0];
    const int*   ct0      = (const int*)d_in[1];
    const int*   ct1      = (const int*)d_in[2];
    const int*   ct2      = (const int*)d_in[3];
    const int*   lens     = (const int*)d_in[4];
    const float* intervals= (const float*)d_in[5];
    const float* code_emb = (const float*)d_in[6];
    const float* t0e      = (const float*)d_in[7];
    const float* t1e      = (const float*)d_in[8];
    const float* t2e      = (const float*)d_in[9];
    const float* Wq       = (const float*)d_in[10];
    const float* Wk       = (const float*)d_in[11];
    const float* Wv       = (const float*)d_in[12];
    const float* time_w   = (const float*)d_in[13];
    const float* time_b   = (const float*)d_in[14];
    const float* gWih     = (const float*)d_in[15];
    const float* gWhh     = (const float*)d_in[16];
    const float* gbih     = (const float*)d_in[17];
    const float* gbhh     = (const float*)d_in[18];
    const float* clsW     = (const float*)d_in[19];
    const float* clsb     = (const float*)d_in[20];

    char* ws = (char*)d_ws;
    const size_t ET_OFF   = 0;              // 256*4096*2      = 2,097,152
    const size_t WCAT_OFF = 2097152;        // 512*256*2       =   262,144
    const size_t WIH_OFF  = 2359296;        // 1536*320*2      =   983,040
    const size_t WHH_OFF  = 3342336;        // 1536*512*2      = 1,572,864
    const size_t V_OFF    = 4915200;        // 6400*256*2      = 3,276,800
    const size_t QKV_OFF  = 8192000;        // 6432*512*2      = 6,586,368 (32 pad rows)
    const size_t X_OFF    = 14778368;       // 6400*320*2      = 4,096,000
    const size_t GI_OFF   = 18874368;       // 6400*1536*2     = 19,660,800
    const size_t HB0_OFF  = 38535168;       // 64*512*2        =    65,536
    const size_t HB1_OFF  = 38600704;       // 64*512*2        =    65,536
    const size_t HB2_OFF  = 38666240;       // 64*512*2 (overlays old hf region, now unused)
    const size_t FLG_OFF  = 38797312;       // 4096 (kept for layout compat; unused)

    unsigned short* ET   = (unsigned short*)(ws + ET_OFF);
    unsigned short* WCAT = (unsigned short*)(ws + WCAT_OFF);
    unsigned short* WIH  = (unsigned short*)(ws + WIH_OFF);
    unsigned short* WHH  = (unsigned short*)(ws + WHH_OFF);
    unsigned short* Vb   = (unsigned short*)(ws + V_OFF);
    unsigned short* QKV  = (unsigned short*)(ws + QKV_OFF);
    unsigned short* Xb   = (unsigned short*)(ws + X_OFF);
    unsigned short* GIb  = (unsigned short*)(ws + GI_OFF);
    unsigned short* hb0  = (unsigned short*)(ws + HB0_OFF);
    unsigned short* hb1  = (unsigned short*)(ws + HB1_OFF);
    unsigned short* hb2  = (unsigned short*)(ws + HB2_OFF);
    int*            flags= (int*)(ws + FLG_OFF);

    init_zero<<<8, 256, 0, stream>>>(flags, hb0, hb1, hb2);
    prep_w<<<512, 256, 0, stream>>>(Wq, Wk, Wv, gWih, gWhh, WCAT, WIH, WHH);
    prep_et<<<dim3(4, 64), 256, 0, stream>>>(code_emb, ct0, ct1, ct2, t0e, t1e, t2e, ET);
    enc_gemm<<<200, 256, 0, stream>>>(code_x, ET, lens, Vb);
    gemm_bf16<<<dim3(200, 2), 256, 0, stream>>>(Vb, WCAT, 256, 512, 2, QKV, nullptr);
    attn_kernel<<<64, 256, 0, stream>>>(QKV, lens, intervals, time_w, time_b, Xb);
    gemm_bf16<<<dim3(200, 6), 256, 0, stream>>>(Xb, WIH, 320, 1536, 1, GIb, gbih);
    gru_kernel<<<32, 256, 0, stream>>>(GIb, WHH, gbhh, lens, hb0, hb1, hb2, clsW, clsb, (float*)d_out);
}

// Round 4
// 768.915 us; speedup vs baseline: 1.1164x; 1.1164x over previous
//
#include <hip/hip_runtime.h>
#include <hip/hip_bf16.h>

typedef float  f32x4 __attribute__((ext_vector_type(4)));
typedef short  s16x8 __attribute__((ext_vector_type(8)));

#define NEGBIG -1e30f

__device__ __forceinline__ unsigned short f2b(float f) {
    union { float f; unsigned u; } c; c.f = f;
    unsigned r = c.u + 0x7FFF + ((c.u >> 16) & 1);
    return (unsigned short)(r >> 16);
}
__device__ __forceinline__ float b2f(unsigned short h) {
    union { unsigned u; float f; } c; c.u = ((unsigned)h) << 16;
    return c.f;
}
__device__ __forceinline__ float sigm(float x) { return 1.f / (1.f + __expf(-x)); }

// coherent (agent-scope) accessors: bypass per-XCD L1/L2, hit the memory-side coherence point.
__device__ __forceinline__ s16x8 ld_b128_sc(const unsigned short* p) {
    s16x8 r;
    asm volatile("global_load_dwordx4 %0, %1, off sc0 sc1" : "=v"(r) : "v"(p));
    return r;
}
__device__ __forceinline__ void st_short_sc(unsigned short* p, unsigned short v) {
    unsigned int dv = v;
    asm volatile("global_store_short %0, %1, off sc0 sc1" :: "v"(p), "v"(dv) : "memory");
}

// ---------------------------------------------------------------- init
__global__ void init_zero(int* flags, unsigned short* hb0) {
    int idx = blockIdx.x * 256 + threadIdx.x;
    int stride = gridDim.x * 256;
    for (int i = idx; i < 1024; i += stride) flags[i] = 0;
    for (int i = idx; i < 32768; i += stride) hb0[i] = 0;
}

// ---------------------------------------------------------------- prep weights (bf16 casts + Wqkv concat-transpose)
__global__ void prep_w(const float* Wq, const float* Wk, const float* Wv,
                       const float* gWih, const float* gWhh,
                       unsigned short* wcat, unsigned short* wih, unsigned short* whh) {
    int idx = blockIdx.x * 256 + threadIdx.x;
    int stride = gridDim.x * 256;
    const int N1 = 131072, N2 = 491520, N3 = 786432;
    for (; idx < N1 + N2 + N3; idx += stride) {
        if (idx < N1) {
            int n = idx >> 8, k = idx & 255;
            float v;
            if (n < 128) v = Wq[k * 128 + n];
            else if (n < 256) v = Wk[k * 128 + (n - 128)];
            else v = Wv[k * 256 + (n - 256)];
            wcat[n * 256 + k] = f2b(v);
        } else if (idx < N1 + N2) {
            int i = idx - N1; wih[i] = f2b(gWih[i]);
        } else {
            int i = idx - N1 - N2; whh[i] = f2b(gWhh[i]);
        }
    }
}

// ---------------------------------------------------------------- prep E^T  [256][4096] bf16
__global__ __launch_bounds__(256) void prep_et(const float* code_emb, const int* ct0, const int* ct1, const int* ct2,
                                               const float* t0e, const float* t1e, const float* t2e,
                                               unsigned short* ET) {
    __shared__ float tile[64][65];
    const int d0 = blockIdx.x * 64, c0 = blockIdx.y * 64;
    const int t = threadIdx.x;
    for (int p = 0; p < 16; ++p) {
        int idx = p * 256 + t;
        int dl = idx & 63, cl = idx >> 6;   // cl in [0,64) over passes
        int code = c0 + cl + 1;
        int d = d0 + dl;
        float v = code_emb[code * 256 + d] + t0e[ct0[code] * 256 + d]
                + t1e[ct1[code] * 256 + d] + t2e[ct2[code] * 256 + d];
        tile[dl][cl] = v;
    }
    __syncthreads();
    for (int p = 0; p < 2; ++p) {
        int idx = p * 256 + t;
        int dl = idx >> 3, ch = idx & 7;
        s16x8 pk;
#pragma unroll
        for (int e = 0; e < 8; ++e) pk[e] = (short)f2b(tile[dl][ch * 8 + e]);
        *(s16x8*)(ET + (size_t)(d0 + dl) * 4096 + c0 + ch * 8) = pk;
    }
}

// ---------------------------------------------------------------- encoder GEMM: v = mask*( (code_x>0) @ E ) / counts
__global__ __launch_bounds__(256) void enc_gemm(const float* code_x, const unsigned short* ET,
                                                const int* lens, unsigned short* Vb) {
    __shared__ __align__(16) char sm[4096 + 32768 + 128];
    char* As = sm;
    char* Bs = sm + 4096;
    float* cl = (float*)(sm + 4096 + 32768);
    const int m0 = blockIdx.x * 32;
    const int t = threadIdx.x, l = t & 63, w = t >> 6;
    const int lr = l & 15, lq = l >> 4, l7 = l & 7;
    const int sr = t >> 3, sc = t & 7;
    f32x4 acc[2][4];
#pragma unroll
    for (int a = 0; a < 2; ++a)
#pragma unroll
        for (int b = 0; b < 4; ++b) acc[a][b] = (f32x4){0.f, 0.f, 0.f, 0.f};
    int cnt = 0;
    for (int it = 0; it < 64; ++it) {
        const int k0 = it * 64;
        const float* ga = code_x + (size_t)(m0 + sr) * 4096 + k0 + sc * 8;
        f32x4 a0 = *(const f32x4*)ga;
        f32x4 a1 = *(const f32x4*)(ga + 4);
        s16x8 ap;
#pragma unroll
        for (int e = 0; e < 4; ++e) { bool on = a0[e] > 0.f; ap[e] = on ? (short)0x3F80 : (short)0; cnt += on ? 1 : 0; }
#pragma unroll
        for (int e = 0; e < 4; ++e) { bool on = a1[e] > 0.f; ap[4 + e] = on ? (short)0x3F80 : (short)0; cnt += on ? 1 : 0; }
        *(s16x8*)(As + sr * 128 + ((sc ^ (sr & 7)) << 4)) = ap;
#pragma unroll
        for (int rd = 0; rd < 8; ++rd) {
            int i = rd * 256 + t;
            int n = i >> 3, cc = i & 7;
            s16x8 bv = *(const s16x8*)(ET + (size_t)n * 4096 + k0 + cc * 8);
            *(s16x8*)(Bs + n * 128 + ((cc ^ (n & 7)) << 4)) = bv;
        }
        __syncthreads();
#pragma unroll
        for (int kk = 0; kk < 2; ++kk) {
            const int cp = kk * 4 + lq;
            s16x8 af[2], bf[4];
#pragma unroll
            for (int mt = 0; mt < 2; ++mt)
                af[mt] = *(const s16x8*)(As + (mt * 16 + lr) * 128 + ((cp ^ l7) << 4));
#pragma unroll
            for (int nt = 0; nt < 4; ++nt)
                bf[nt] = *(const s16x8*)(Bs + ((w * 4 + nt) * 16 + lr) * 128 + ((cp ^ l7) << 4));
#pragma unroll
            for (int mt = 0; mt < 2; ++mt)
#pragma unroll
                for (int nt = 0; nt < 4; ++nt)
                    acc[mt][nt] = __builtin_amdgcn_mfma_f32_16x16x32_bf16(af[mt], bf[nt], acc[mt][nt], 0, 0, 0);
        }
        __syncthreads();
    }
    float fc = (float)cnt;
    fc += __shfl_xor(fc, 1); fc += __shfl_xor(fc, 2); fc += __shfl_xor(fc, 4);
    if (sc == 0) cl[sr] = fmaxf(fc, 1.f);
    __syncthreads();
#pragma unroll
    for (int mt = 0; mt < 2; ++mt)
#pragma unroll
        for (int i = 0; i < 4; ++i) {
            int m = mt * 16 + lq * 4 + i;
            int gm = m0 + m;
            float rc = 1.f / cl[m];
            unsigned bi = (unsigned)gm / 100u;
            unsigned vi = (unsigned)gm - bi * 100u;
            float msk = ((int)vi < lens[bi]) ? 1.f : 0.f;
#pragma unroll
            for (int nt = 0; nt < 4; ++nt) {
                int n = (w * 4 + nt) * 16 + lr;
                Vb[(size_t)gm * 256 + n] = f2b(acc[mt][nt][i] * rc * msk);
            }
        }
}

// ---------------------------------------------------------------- generic bf16 GEMM (A[M][K] @ B[N][K]^T), M tiled by 32, N by 256
// mode 1: out bf16 plain + bias; mode 2: out bf16 plain, no bias
__global__ __launch_bounds__(256) void gemm_bf16(const unsigned short* A, const unsigned short* Bm,
                                                 int K, int Ntot, int mode,
                                                 unsigned short* outp, const float* bias) {
    __shared__ __align__(16) char sm[4096 + 32768];
    char* As = sm;
    char* Bs = sm + 4096;
    const int m0 = blockIdx.x * 32;
    const int n0 = blockIdx.y * 256;
    const int t = threadIdx.x, l = t & 63, w = t >> 6;
    const int lr = l & 15, lq = l >> 4, l7 = l & 7;
    const int sr = t >> 3, sc = t & 7;
    const int iters = K >> 6;
    f32x4 acc[2][4];
#pragma unroll
    for (int a = 0; a < 2; ++a)
#pragma unroll
        for (int b = 0; b < 4; ++b) acc[a][b] = (f32x4){0.f, 0.f, 0.f, 0.f};
    for (int it = 0; it < iters; ++it) {
        const int k0 = it * 64;
        s16x8 av = *(const s16x8*)(A + (size_t)(m0 + sr) * K + k0 + sc * 8);
        *(s16x8*)(As + sr * 128 + ((sc ^ (sr & 7)) << 4)) = av;
#pragma unroll
        for (int rd = 0; rd < 8; ++rd) {
            int i = rd * 256 + t;
            int n = i >> 3, cc = i & 7;
            s16x8 bv = *(const s16x8*)(Bm + (size_t)(n0 + n) * K + k0 + cc * 8);
            *(s16x8*)(Bs + n * 128 + ((cc ^ (n & 7)) << 4)) = bv;
        }
        __syncthreads();
#pragma unroll
        for (int kk = 0; kk < 2; ++kk) {
            const int cp = kk * 4 + lq;
            s16x8 af[2], bf[4];
#pragma unroll
            for (int mt = 0; mt < 2; ++mt)
                af[mt] = *(const s16x8*)(As + (mt * 16 + lr) * 128 + ((cp ^ l7) << 4));
#pragma unroll
            for (int nt = 0; nt < 4; ++nt)
                bf[nt] = *(const s16x8*)(Bs + ((w * 4 + nt) * 16 + lr) * 128 + ((cp ^ l7) << 4));
#pragma unroll
            for (int mt = 0; mt < 2; ++mt)
#pragma unroll
                for (int nt = 0; nt < 4; ++nt)
                    acc[mt][nt] = __builtin_amdgcn_mfma_f32_16x16x32_bf16(af[mt], bf[nt], acc[mt][nt], 0, 0, 0);
        }
        __syncthreads();
    }
#pragma unroll
    for (int mt = 0; mt < 2; ++mt)
#pragma unroll
        for (int i = 0; i < 4; ++i) {
            int gm = m0 + mt * 16 + lq * 4 + i;
#pragma unroll
            for (int nt = 0; nt < 4; ++nt) {
                int n = n0 + (w * 4 + nt) * 16 + lr;
                float v = acc[mt][nt][i];
                if (mode == 1) v += bias[n];
                outp[(size_t)gm * Ntot + n] = f2b(v);
            }
        }
}

// ---------------------------------------------------------------- attention (one block per batch) + time-emb concat
__global__ __launch_bounds__(256) void attn_kernel(const unsigned short* QKV, const int* lens,
                                                   const float* intervals, const float* time_w, const float* time_b,
                                                   unsigned short* X) {
    __shared__ __align__(16) char sm[28672 + 32768];
    char* Pb = sm;            // P: 112 rows x 128 cols bf16, pitch 256B, swizzled
    char* VTb = sm + 28672;   // V^T half: 128 d x 128 j bf16, pitch 256B, swizzled
    const int b = blockIdx.x;
    const int t = threadIdx.x, l = t & 63, w = t >> 6;
    const int lr = l & 15, lq = l >> 4;
    const int lenb = lens[b];
    // zero P
    for (int p = 0; p < 7; ++p) {
        int idx = p * 256 + t;
        *(f32x4*)(Pb + idx * 16) = (f32x4){0.f, 0.f, 0.f, 0.f};
    }
    __syncthreads();
    // ---- S = Q K^T  (rows 2w..2w+1 tiles of 16; wave 3 handles tile 6 only)
    f32x4 S[2][7];
#pragma unroll
    for (int a = 0; a < 2; ++a)
#pragma unroll
        for (int c = 0; c < 7; ++c) S[a][c] = (f32x4){0.f, 0.f, 0.f, 0.f};
#pragma unroll
    for (int kk = 0; kk < 4; ++kk) {
        s16x8 qa[2], kb[7];
#pragma unroll
        for (int mi = 0; mi < 2; ++mi) {
            int mt = 2 * w + mi;
            if (mt > 6) continue;
            int row = b * 100 + mt * 16 + lr;
            qa[mi] = *(const s16x8*)(QKV + (size_t)row * 512 + kk * 32 + lq * 8);
        }
#pragma unroll
        for (int nt = 0; nt < 7; ++nt) {
            int row = b * 100 + nt * 16 + lr;
            kb[nt] = *(const s16x8*)(QKV + (size_t)row * 512 + 128 + kk * 32 + lq * 8);
        }
#pragma unroll
        for (int mi = 0; mi < 2; ++mi) {
            int mt = 2 * w + mi;
            if (mt > 6) continue;
#pragma unroll
            for (int nt = 0; nt < 7; ++nt)
                S[mi][nt] = __builtin_amdgcn_mfma_f32_16x16x32_bf16(qa[mi], kb[nt], S[mi][nt], 0, 0, 0);
        }
    }
    // ---- softmax rows (all in shuffle groups of 16), store P to LDS
#pragma unroll
    for (int mi = 0; mi < 2; ++mi) {
        int mt = 2 * w + mi;
        if (mt > 6) continue;
        float sv[7][4];
#pragma unroll
        for (int nt = 0; nt < 7; ++nt) {
            int j = nt * 16 + lr;
#pragma unroll
            for (int i = 0; i < 4; ++i)
                sv[nt][i] = (j < lenb) ? S[mi][nt][i] : NEGBIG;
        }
#pragma unroll
        for (int i = 0; i < 4; ++i) {
            float mx = sv[0][i];
#pragma unroll
            for (int nt = 1; nt < 7; ++nt) mx = fmaxf(mx, sv[nt][i]);
            mx = fmaxf(mx, __shfl_xor(mx, 1));
            mx = fmaxf(mx, __shfl_xor(mx, 2));
            mx = fmaxf(mx, __shfl_xor(mx, 4));
            mx = fmaxf(mx, __shfl_xor(mx, 8));
            float e[7], sum = 0.f;
#pragma unroll
            for (int nt = 0; nt < 7; ++nt) { e[nt] = __expf(sv[nt][i] - mx); sum += e[nt]; }
            sum += __shfl_xor(sum, 1);
            sum += __shfl_xor(sum, 2);
            sum += __shfl_xor(sum, 4);
            sum += __shfl_xor(sum, 8);
            float rs = 1.f / sum;
            int m = mt * 16 + lq * 4 + i;
#pragma unroll
            for (int nt = 0; nt < 7; ++nt) {
                int j = nt * 16 + lr;
                *(unsigned short*)(Pb + m * 256 + (((j >> 3) ^ (m & 7)) << 4) + ((j & 7) << 1)) = f2b(e[nt] * rs);
            }
        }
    }
    __syncthreads();
    // ---- O = P @ V + V, two halves of d
    for (int h = 0; h < 2; ++h) {
        for (int p = 0; p < 8; ++p) {
            int idx = p * 256 + t;
            *(f32x4*)(VTb + idx * 16) = (f32x4){0.f, 0.f, 0.f, 0.f};
        }
        __syncthreads();
        for (int p = 0; p < 7; ++p) {
            int ci = p * 256 + t;
            if (ci < 1600) {
                int j = ci >> 4, d8 = ci & 15;
                s16x8 vv = *(const s16x8*)(QKV + (size_t)(b * 100 + j) * 512 + 256 + h * 128 + d8 * 8);
#pragma unroll
                for (int e = 0; e < 8; ++e) {
                    int dl = d8 * 8 + e;
                    *(unsigned short*)(VTb + dl * 256 + (((j >> 3) ^ (dl & 7)) << 4) + ((j & 7) << 1)) = (unsigned short)vv[e];
                }
            }
        }
        __syncthreads();
        f32x4 O[2][8];
#pragma unroll
        for (int a = 0; a < 2; ++a)
#pragma unroll
            for (int c = 0; c < 8; ++c) O[a][c] = (f32x4){0.f, 0.f, 0.f, 0.f};
#pragma unroll
        for (int kk = 0; kk < 4; ++kk) {
            s16x8 pa[2];
#pragma unroll
            for (int mi = 0; mi < 2; ++mi) {
                int mt = 2 * w + mi;
                if (mt > 6) continue;
                int m = mt * 16 + lr;
                pa[mi] = *(const s16x8*)(Pb + m * 256 + (((kk * 4 + lq) ^ (m & 7)) << 4));
            }
#pragma unroll
            for (int nt = 0; nt < 8; ++nt) {
                int dl = nt * 16 + lr;
                s16x8 vb = *(const s16x8*)(VTb + dl * 256 + (((kk * 4 + lq) ^ (dl & 7)) << 4));
#pragma unroll
                for (int mi = 0; mi < 2; ++mi) {
                    int mt = 2 * w + mi;
                    if (mt > 6) continue;
                    O[mi][nt] = __builtin_amdgcn_mfma_f32_16x16x32_bf16(pa[mi], vb, O[mi][nt], 0, 0, 0);
                }
            }
        }
#pragma unroll
        for (int mi = 0; mi < 2; ++mi) {
            int mt = 2 * w + mi;
            if (mt > 6) continue;
#pragma unroll
            for (int i = 0; i < 4; ++i) {
                int m = mt * 16 + lq * 4 + i;
                if (m < 100) {
#pragma unroll
                    for (int nt = 0; nt < 8; ++nt) {
                        int dl = nt * 16 + lr;
                        float res = b2f(*(unsigned short*)(VTb + dl * 256 + (((m >> 3) ^ (dl & 7)) << 4) + ((m & 7) << 1)));
                        X[(size_t)(b * 100 + m) * 320 + h * 128 + dl] = f2b(O[mi][nt][i] + res);
                    }
                }
            }
        }
        if (h == 0) __syncthreads();
    }
    // ---- time embedding
    for (int p = 0; p < 25; ++p) {
        int idx = p * 256 + t;
        int m = idx >> 6, d = idx & 63;
        float val = intervals[b * 100 + m] * time_w[d] + time_b[d];
        X[(size_t)(b * 100 + m) * 320 + 256 + d] = f2b(val);
    }
}

// ---------------------------------------------------------------- GRU recurrence + classifier.
// r2 flag protocol (verified 438us), upgraded two ways:
//  (1) Bf (Whh slice, 192 VGPRs) is PINNED in registers via per-iteration empty "+v" asm —
//      without it the compiler rematerializes 48x16B/thread from L2 every step (~1.4us/step,
//      the VGPR_Count=168<192 smoking gun).
//  (2) plane-decoupled barrier: wave w only reads h rows of batches [16w,16w+16), written by
//      waves w of all blocks. Per-wave flags; no __syncthreads in the loop at all.
__global__ __launch_bounds__(256, 1) void gru_kernel(const unsigned short* GIb, const unsigned short* WHH,
                                                     const float* gbhh, const int* lens,
                                                     unsigned short* hb0, unsigned short* hb1,
                                                     int* flags, const float* clsW, const float* clsb, float* out) {
    const int bid = blockIdx.x;
    const int t = threadIdx.x, l = t & 63, w = t >> 6;
    const int lr = l & 15, lq = l >> 4;
    const int j = bid * 16 + lr;
    // max length (uniform across blocks)
    int ml;
    {
        int v = lens[l];
        v = max(v, __shfl_xor(v, 1));  v = max(v, __shfl_xor(v, 2));
        v = max(v, __shfl_xor(v, 4));  v = max(v, __shfl_xor(v, 8));
        v = max(v, __shfl_xor(v, 16)); v = max(v, __shfl_xor(v, 32));
        ml = v;
    }
    int lens4[4];
#pragma unroll
    for (int i = 0; i < 4; ++i) lens4[i] = lens[w * 16 + lq * 4 + i];
    const float bhr = gbhh[j], bhz = gbhh[512 + j], bhn = gbhh[1024 + j];
    // Whh fragment slice: 3 gates x 16 k-steps, loaded once, pinned resident in the loop
    s16x8 Bf[3][16];
#pragma unroll
    for (int g = 0; g < 3; ++g)
#pragma unroll
        for (int kk = 0; kk < 16; ++kk)
            Bf[g][kk] = *(const s16x8*)(WHH + (size_t)(g * 512 + j) * 512 + kk * 32 + lq * 8);
    float ho[4] = {0.f, 0.f, 0.f, 0.f};
    size_t gi_base[4];
    size_t hrow[4];
#pragma unroll
    for (int i = 0; i < 4; ++i) {
        gi_base[i] = (size_t)((w * 16 + lq * 4 + i) * 100) * 1536 + j;
        hrow[i]    = (size_t)(w * 16 + lq * 4 + i) * 512 + j;
    }
    const size_t arow = (size_t)(w * 16 + lr) * 512 + lq * 8;
    const int myflag = (bid * 4 + w) * 8;

    // prefetch gi for step 0 (plain cached loads; GIb read-only)
    float gir[4], giz[4], gin[4];
#pragma unroll
    for (int i = 0; i < 4; ++i) {
        const unsigned short* gp = GIb + gi_base[i];
        gir[i] = b2f(gp[0]); giz[i] = b2f(gp[512]); gin[i] = b2f(gp[1024]);
    }

    for (int step = 0; step < ml; ++step) {
        const unsigned short* hb = (step & 1) ? hb1 : hb0;
        unsigned short* hn = (step & 1) ? hb0 : hb1;
        // pin Whh residency: remat/spill-reload of Bf becomes illegal inside the loop
#pragma unroll
        for (int g = 0; g < 3; ++g)
#pragma unroll
            for (int kk = 0; kk < 16; ++kk)
                asm volatile("" : "+v"(Bf[g][kk]));
        // coherent load of plane-w h rows (bypasses stale L1/L2)
        s16x8 af[16];
#pragma unroll
        for (int kk = 0; kk < 16; ++kk)
            af[kk] = ld_b128_sc(hb + arow + kk * 32);
        asm volatile("s_waitcnt vmcnt(0)" ::: "memory");
        __builtin_amdgcn_sched_barrier(0);   // keep MFMAs below the wait (asm loads not dep-tracked)
        f32x4 ar = (f32x4){0.f,0.f,0.f,0.f}, az = ar, an = ar;
#pragma unroll
        for (int kk = 0; kk < 16; ++kk) {
            ar = __builtin_amdgcn_mfma_f32_16x16x32_bf16(af[kk], Bf[0][kk], ar, 0, 0, 0);
            az = __builtin_amdgcn_mfma_f32_16x16x32_bf16(af[kk], Bf[1][kk], az, 0, 0, 0);
            an = __builtin_amdgcn_mfma_f32_16x16x32_bf16(af[kk], Bf[2][kk], an, 0, 0, 0);
        }
#pragma unroll
        for (int i = 0; i < 4; ++i) {
            float r = sigm(gir[i] + ar[i] + bhr);
            float z = sigm(giz[i] + az[i] + bhz);
            float n = tanhf(gin[i] + r * (an[i] + bhn));
            float hv = (step < lens4[i]) ? ((1.f - z) * n + z * ho[i]) : ho[i];
            ho[i] = hv;
            st_short_sc(hn + hrow[i], f2b(hv));
        }
        // publish plane-w progress: drain store-acks, arm per-wave flag, prefetch, poll plane
        asm volatile("s_waitcnt vmcnt(0)" ::: "memory");
        if (l == 0)
            __hip_atomic_store(flags + myflag, step + 1, __ATOMIC_RELAXED, __HIP_MEMORY_SCOPE_AGENT);
        if (step + 1 < ml) {
#pragma unroll
            for (int i = 0; i < 4; ++i) {
                const unsigned short* gp = GIb + gi_base[i] + (size_t)(step + 1) * 1536;
                gir[i] = b2f(gp[0]); giz[i] = b2f(gp[512]); gin[i] = b2f(gp[1024]);
            }
        }
        {
            int guard = 0;
            while (true) {
                int v = (l < 32) ? __hip_atomic_load(flags + (l * 4 + w) * 8, __ATOMIC_RELAXED, __HIP_MEMORY_SCOPE_AGENT) : (step + 1);
                if (__all(v >= step + 1)) break;
                if (++guard > (1 << 20)) break;  // safety: no hang
                __builtin_amdgcn_s_sleep(1);
            }
        }
        __builtin_amdgcn_sched_barrier(0);
    }

    // classifier: 30 blocks x 3 output columns over the final h (bf16 parity buffer).
    // Needs ALL planes done: poll all 128 per-wave flags >= ml, then plain-read
    // (no stale local lines exist: h only ever touched via sc ops this dispatch).
    if (bid < 30) {
        {
            int guard = 0;
            while (true) {
                int v = ml;
                if (l < 32) {
                    int v0 = __hip_atomic_load(flags + (l * 4 + 0) * 8, __ATOMIC_RELAXED, __HIP_MEMORY_SCOPE_AGENT);
                    int v1 = __hip_atomic_load(flags + (l * 4 + 1) * 8, __ATOMIC_RELAXED, __HIP_MEMORY_SCOPE_AGENT);
                    int v2 = __hip_atomic_load(flags + (l * 4 + 2) * 8, __ATOMIC_RELAXED, __HIP_MEMORY_SCOPE_AGENT);
                    int v3 = __hip_atomic_load(flags + (l * 4 + 3) * 8, __ATOMIC_RELAXED, __HIP_MEMORY_SCOPE_AGENT);
                    v = min(min(v0, v1), min(v2, v3));
                }
                if (__all(v >= ml)) break;
                if (++guard > (1 << 20)) break;
                __builtin_amdgcn_s_sleep(1);
            }
        }
        __builtin_amdgcn_sched_barrier(0);
        const unsigned short* fbuf = (ml & 1) ? hb1 : hb0;   // written at step ml-1
        int bb = t >> 2, qq = t & 3;
        int c0 = bid * 3;
        float s0 = 0.f, s1 = 0.f, s2 = 0.f;
        for (int kc = 0; kc < 16; ++kc) {
            int k = qq * 128 + kc * 8;
            s16x8 hvb = *(const s16x8*)(fbuf + (size_t)bb * 512 + k);
            f32x4 w0a = *(const f32x4*)(clsW + (size_t)(c0 + 0) * 512 + k);
            f32x4 w0b = *(const f32x4*)(clsW + (size_t)(c0 + 0) * 512 + k + 4);
            f32x4 w1a = *(const f32x4*)(clsW + (size_t)(c0 + 1) * 512 + k);
            f32x4 w1b = *(const f32x4*)(clsW + (size_t)(c0 + 1) * 512 + k + 4);
            f32x4 w2a = *(const f32x4*)(clsW + (size_t)(c0 + 2) * 512 + k);
            f32x4 w2b = *(const f32x4*)(clsW + (size_t)(c0 + 2) * 512 + k + 4);
#pragma unroll
            for (int e = 0; e < 4; ++e) {
                float h0 = b2f((unsigned short)hvb[e]);
                float h1 = b2f((unsigned short)hvb[4 + e]);
                s0 += h0 * w0a[e] + h1 * w0b[e];
                s1 += h0 * w1a[e] + h1 * w1b[e];
                s2 += h0 * w2a[e] + h1 * w2b[e];
            }
        }
        s0 += __shfl_xor(s0, 1); s0 += __shfl_xor(s0, 2);
        s1 += __shfl_xor(s1, 1); s1 += __shfl_xor(s1, 2);
        s2 += __shfl_xor(s2, 1); s2 += __shfl_xor(s2, 2);
        if (qq == 0) {
            out[bb * 90 + c0 + 0] = sigm(s0 + clsb[c0 + 0]);
            out[bb * 90 + c0 + 1] = sigm(s1 + clsb[c0 + 1]);
            out[bb * 90 + c0 + 2] = sigm(s2 + clsb[c0 + 2]);
        }
    }
}

// ---------------------------------------------------------------- launch
extern "C" void kernel_launch(void* const* d_in, const int* in_sizes, int n_in,
                              void* d_out, int out_size, void* d_ws, size_t ws_size,
                              hipStream_t stream) {
    const float* code_x   = (const float*)d_in[0];
    const int*   ct0      = (const int*)d_in[1];
    const int*   ct1      = (const int*)d_in[2];
    const int*   ct2      = (const int*)d_in[3];
    const int*   lens     = (const int*)d_in[4];
    const float* intervals= (const float*)d_in[5];
    const float* code_emb = (const float*)d_in[6];
    const float* t0e      = (const float*)d_in[7];
    const float* t1e      = (const float*)d_in[8];
    const float* t2e      = (const float*)d_in[9];
    const float* Wq       = (const float*)d_in[10];
    const float* Wk       = (const float*)d_in[11];
    const float* Wv       = (const float*)d_in[12];
    const float* time_w   = (const float*)d_in[13];
    const float* time_b   = (const float*)d_in[14];
    const float* gWih     = (const float*)d_in[15];
    const float* gWhh     = (const float*)d_in[16];
    const float* gbih     = (const float*)d_in[17];
    const float* gbhh     = (const float*)d_in[18];
    const float* clsW     = (const float*)d_in[19];
    const float* clsb     = (const float*)d_in[20];

    char* ws = (char*)d_ws;
    const size_t ET_OFF   = 0;              // 256*4096*2      = 2,097,152
    const size_t WCAT_OFF = 2097152;        // 512*256*2       =   262,144
    const size_t WIH_OFF  = 2359296;        // 1536*320*2      =   983,040
    const size_t WHH_OFF  = 3342336;        // 1536*512*2      = 1,572,864
    const size_t V_OFF    = 4915200;        // 6400*256*2      = 3,276,800
    const size_t QKV_OFF  = 8192000;        // 6432*512*2      = 6,586,368 (32 pad rows)
    const size_t X_OFF    = 14778368;       // 6400*320*2      = 4,096,000
    const size_t GI_OFF   = 18874368;       // 6400*1536*2     = 19,660,800
    const size_t HB0_OFF  = 38535168;       // 64*512*2        =    65,536
    const size_t HB1_OFF  = 38600704;       // 64*512*2        =    65,536
    const size_t FLG_OFF  = 38797312;       // 1024 ints       =     4,096

    unsigned short* ET   = (unsigned short*)(ws + ET_OFF);
    unsigned short* WCAT = (unsigned short*)(ws + WCAT_OFF);
    unsigned short* WIH  = (unsigned short*)(ws + WIH_OFF);
    unsigned short* WHH  = (unsigned short*)(ws + WHH_OFF);
    unsigned short* Vb   = (unsigned short*)(ws + V_OFF);
    unsigned short* QKV  = (unsigned short*)(ws + QKV_OFF);
    unsigned short* Xb   = (unsigned short*)(ws + X_OFF);
    unsigned short* GIb  = (unsigned short*)(ws + GI_OFF);
    unsigned short* hb0  = (unsigned short*)(ws + HB0_OFF);
    unsigned short* hb1  = (unsigned short*)(ws + HB1_OFF);
    int*            flags= (int*)(ws + FLG_OFF);

    init_zero<<<8, 256, 0, stream>>>(flags, hb0);
    prep_w<<<512, 256, 0, stream>>>(Wq, Wk, Wv, gWih, gWhh, WCAT, WIH, WHH);
    prep_et<<<dim3(4, 64), 256, 0, stream>>>(code_emb, ct0, ct1, ct2, t0e, t1e, t2e, ET);
    enc_gemm<<<200, 256, 0, stream>>>(code_x, ET, lens, Vb);
    gemm_bf16<<<dim3(200, 2), 256, 0, stream>>>(Vb, WCAT, 256, 512, 2, QKV, nullptr);
    attn_kernel<<<64, 256, 0, stream>>>(QKV, lens, intervals, time_w, time_b, Xb);
    gemm_bf16<<<dim3(200, 6), 256, 0, stream>>>(Xb, WIH, 320, 1536, 1, GIb, gbih);
    gru_kernel<<<32, 256, 0, stream>>>(GIb, WHH, gbhh, lens, hb0, hb1, flags, clsW, clsb, (float*)d_out);
}